// Round 8
// baseline (37.064 us; speedup 1.0000x reference)
//
#include <hip/hip_runtime.h>
#include <hip/hip_bf16.h>

// Locally-connected 2D conv via MFMA (bf16 inputs, fp32 accumulate).
// x:(8,32,64,64)  weights:(64,64,32,32,3,3)  bias:(32)  out:(8,32,64,64)
// out[b,o,i,j] = bias[o] + sum_k xpatch[b,k] * W[loc][o][k],  k=c*9+a*3+bb,
//   xpatch[b,k] = x[b, c, i+bb-1, j+a-1]   (a=col offset, bb=row offset)
//
// R7: 1024 WGs x 512 thr, LOCS=4, one wave per (loc, o-tile) phase ->
// 32 waves/CU in a single co-resident round (grid = 4 WGs/CU exactly).
// Per wave: 9 x-stage loads -> 18 weight dwordx4 (in flight across both
// barriers; in-order vmcnt, stage loads issued first) -> A-frag gather
// straight from padded xnat into regs (no xtb LDS stage, no build barrier;
// per-b stride 578 spreads the 8 b-rows across banks) -> 9 MFMA with HW
// bf16 cvt -> obuf -> one float4 NCHW store per (b,o) thread.
// MFMA frag/D layouts identical to R5/R6 (numerically verified).

#define NB 8
#define NC 32
#define NO 32
#define NH 64
#define NW 64
#define KK 288
#define LOCS 4
#define XCOLS 6                        // j0-1 .. j0+4
#define BSTRIDE 578                    // 96 rows * 6 cols + 2 pad (bank spread)
#define XNAT_SZ (NB * BSTRIDE)         // 4624 floats = 18496 B

typedef __attribute__((ext_vector_type(8))) short s16x8;
typedef __attribute__((ext_vector_type(4))) float f32x4;

union Frag { unsigned short s[8]; uint4 q; s16x8 v; };

__device__ __forceinline__ unsigned short f2bf(float f) {
  __hip_bfloat16 h = __float2bfloat16(f);   // HW cvt (RNE) on gfx950
  return *reinterpret_cast<unsigned short*>(&h);
}

__global__ __launch_bounds__(512) void lc2d_kernel(
    const float* __restrict__ x, const float* __restrict__ w,
    const float* __restrict__ bias, float* __restrict__ out) {
  const int bid = blockIdx.x;                    // 0..1023
  const int g = (bid & 7) * 128 + (bid >> 3);    // XCD-bijective cluster
  const int loc0 = g * LOCS;
  const int i = loc0 >> 6;                       // 4 | 64 -> same i per WG
  const int j0 = loc0 & 63;
  const int t = threadIdx.x;
  const int lane = t & 63;
  const int wv = t >> 6;                         // wave 0..7
  const int m16 = lane & 15;
  const int kg = lane >> 4;                      // k-group 0..3
  const int l = wv >> 1;                         // this wave's loc (0..3)
  const int ot = wv & 1;                         // this wave's o-tile (0/1)
  const int bm = m16 & 7;                        // this lane's A-row (b)

  __shared__ float xnat[XNAT_SZ];                // 18496 B
  __shared__ float obuf[LOCS][NB][NO];           //  4096 B

  // ---- 1. x-stage loads into regs (issued first; oldest in vmcnt) ----
  // element e = bm*576 + (c*3+yy)*6 + cc  ->  x[b=bm, c, i+yy-1, j0+cc-1]
  float sv[9];
#pragma unroll
  for (int it = 0; it < 9; ++it) {
    int e = t + it * 512;                        // < 4608
    int b_ = e / 576;
    int r = e - b_ * 576;
    int row = r / XCOLS;                         // c*3 + yy
    int cc = r - row * XCOLS;
    int c = row / 3;
    int yy = row - c * 3;
    int y = i + yy - 1;
    int xc = j0 + cc - 1;
    float v = 0.f;
    if ((unsigned)y < 64u && (unsigned)xc < 64u)
      v = x[((b_ * NC + c) * NH + y) * NW + xc];
    sv[it] = v;
  }
  asm volatile("" ::: "memory");  // keep weight-load issue after stage loads

  // ---- 2. weight loads: 18 dwordx4, in flight until the MFMA loop ----
  // lane (m16 = o-in-tile, kg = k-chunk): W[o][ks*32 + kg*8 + 0..7]
  float4 wf[18];
  {
    const float* wp =
        w + ((size_t)(loc0 + l) * NO + ot * 16 + m16) * KK + kg * 8;
#pragma unroll
    for (int ks = 0; ks < 9; ++ks) {
      wf[2 * ks]     = *(const float4*)(wp + ks * 32);
      wf[2 * ks + 1] = *(const float4*)(wp + ks * 32 + 4);
    }
  }

  // ---- 3. publish xnat (ds_writes wait only stage loads: vmcnt(18)) ----
#pragma unroll
  for (int it = 0; it < 9; ++it) {
    int e = t + it * 512;
    int b_ = e / 576;
    int r = e - b_ * 576;
    xnat[b_ * BSTRIDE + r] = sv[it];
  }
  asm volatile("s_waitcnt lgkmcnt(0)\n\ts_barrier" ::: "memory");

  // ---- 4. A-frag gather: lane (m16,kg) row bm, k = ks*32+kg*8+e ----
  // rows 8-15 duplicate 0-7 (D rows 8-15 discarded). Bank-spread by
  // BSTRIDE%32==2.
  uint4 afr[9];
#pragma unroll
  for (int ks = 0; ks < 9; ++ks) {
    Frag f;
#pragma unroll
    for (int e = 0; e < 8; ++e) {
      int k = ks * 32 + kg * 8 + e;
      int c = k / 9;
      int rem = k - c * 9;
      int a = rem / 3;                           // col offset (W axis)
      int bb = rem - a * 3;                      // row offset (H axis)
      f.s[e] = f2bf(xnat[bm * BSTRIDE + (c * 3 + bb) * XCOLS + l + a]);
    }
    afr[ks] = f.q;
  }

  // ---- 5. cvt weights as they land + 9 MFMA ----
  f32x4 acc = {0.f, 0.f, 0.f, 0.f};
#pragma unroll
  for (int ks = 0; ks < 9; ++ks) {
    float4 lo = wf[2 * ks], hi = wf[2 * ks + 1];
    Frag fb;
    fb.s[0] = f2bf(lo.x); fb.s[1] = f2bf(lo.y);
    fb.s[2] = f2bf(lo.z); fb.s[3] = f2bf(lo.w);
    fb.s[4] = f2bf(hi.x); fb.s[5] = f2bf(hi.y);
    fb.s[6] = f2bf(hi.z); fb.s[7] = f2bf(hi.w);
    Frag fa; fa.q = afr[ks];
    acc = __builtin_amdgcn_mfma_f32_16x16x32_bf16(fa.v, fb.v, acc, 0, 0, 0);
  }

  // ---- 6. D: row = kg*4 + r = b, col = m16 = o-in-tile ----
  if (kg < 2) {
#pragma unroll
    for (int r = 0; r < 4; ++r)
      obuf[l][kg * 4 + r][ot * 16 + m16] = acc[r];
  }
  asm volatile("s_waitcnt lgkmcnt(0)\n\ts_barrier" ::: "memory");

  // ---- 7. final store: thread t<256 = (b,o); out[b,o,i,j0..j0+3] ----
  if (t < 256) {
    const int b_ = t >> 5;
    const int o_ = t & 31;
    const float bia = bias[o_];
    float4 r4;
    r4.x = obuf[0][b_][o_] + bia;
    r4.y = obuf[1][b_][o_] + bia;
    r4.z = obuf[2][b_][o_] + bia;
    r4.w = obuf[3][b_][o_] + bia;
    *reinterpret_cast<float4*>(
        &out[((size_t)(b_ * NO + o_) * NH + i) * NW + j0]) = r4;
  }
}

extern "C" void kernel_launch(void* const* d_in, const int* in_sizes, int n_in,
                              void* d_out, int out_size, void* d_ws, size_t ws_size,
                              hipStream_t stream) {
  const float* x    = (const float*)d_in[0];
  const float* w    = (const float*)d_in[1];
  const float* bias = (const float*)d_in[2];
  float* out = (float*)d_out;
  lc2d_kernel<<<dim3(NH * NW / LOCS), dim3(512), 0, stream>>>(x, w, bias, out);
}